// Round 5
// baseline (348.065 us; speedup 1.0000x reference)
//
#include <hip/hip_runtime.h>
#include <hip/hip_bf16.h>

typedef _Float16 half4_t __attribute__((ext_vector_type(4)));
typedef _Float16 half8 __attribute__((ext_vector_type(8)));
typedef float f32x4 __attribute__((ext_vector_type(4)));

#define BB 16
#define HH 64
#define WW2 64
#define CC 256

// ---------------------------------------------------------------------------
// Kernel T: LDS tile transpose of BOTH offset halves to pixel-major f16.
// (validated round 3: reads fully coalesced, writes 128B chunks, pad 65.)
// ---------------------------------------------------------------------------
__global__ __launch_bounds__(256) void k_trans(const float* __restrict__ off,
                                               _Float16* __restrict__ offAT,
                                               _Float16* __restrict__ offBT)
{
  __shared__ _Float16 tile[64][65];
  const int blk = blockIdx.x;          // b(16) * half(2) * cht(4) * st(64)
  const int st   = blk & 63;
  const int cht  = (blk >> 6) & 3;
  const int half = (blk >> 8) & 1;
  const int b    = blk >> 9;
  const int t = threadIdx.x;

  const int s0 = st * 64;
  const int ch0 = half * 256 + cht * 64;
  const float* src = off + ((size_t)b * 512 + ch0) * 4096 + s0;
  const int sl = t & 63;
  #pragma unroll
  for (int p = 0; p < 16; p++) {
    int chl = (t >> 6) + p * 4;
    tile[chl][sl] = (_Float16)src[(size_t)chl * 4096 + sl];
  }
  __syncthreads();

  _Float16* dst = (half == 0) ? offAT : offBT;
  #pragma unroll
  for (int p = 0; p < 2; p++) {
    int pl = (t >> 3) + p * 32;         // pixel within tile
    int c8 = (t & 7) * 8;
    half8 hv;
    #pragma unroll
    for (int r = 0; r < 8; r++) hv[r] = tile[c8 + r][pl];
    int s = s0 + pl;
    size_t pix = (half == 0) ? ((size_t)b * 4096 + s)
                             : ((size_t)b * 4096 + (s & 63) * 64 + (s >> 6));
    *(half8*)(dst + pix * 256 + cht * 64 + c8) = hv;
  }
}

// ---------------------------------------------------------------------------
// Kernel R: sw sampling + depthwise 5x5 conv. Block = (b,y), thread = channel.
// swb ALIASES offA (workspace reuse), so in-loop offset loads would force a
// vmcnt(0) drain every iteration (load-after-maybe-aliasing-store). Fix:
// group-of-10 offset prefetch ring (static reg indices; 10 % 5 == 0 keeps the
// conv ring static too) -> one drain per 10 iterations, loads issued in batch.
// Conv loads come from x (const __restrict__) and pipeline freely.
// ---------------------------------------------------------------------------
__global__ __launch_bounds__(256) void k_row(
    const float* __restrict__ x, const _Float16* offA,
    const float* __restrict__ lw,
    _Float16* swb, _Float16* __restrict__ cvb,
    float* __restrict__ ssw, float* __restrict__ scv)
{
  __shared__ _Float16 xr[WW2 * CC];     // [xi][c], 32 KB

  const int work = (blockIdx.x & 7) * 128 + (blockIdx.x >> 3);  // 1024 blocks
  const int b = work >> 6, y = work & 63;
  const int t = threadIdx.x;
  const int c = t;

  // stage x row -> xr (coalesced float4, f16 convert)
  const float* xrow_src = x + (size_t)(b * HH + y) * WW2 * CC;
  #pragma unroll
  for (int p = 0; p < 16; p++) {
    int i = p * 1024 + t * 4;
    float4 v = *(const float4*)(xrow_src + i);
    half4_t h = {(_Float16)v.x, (_Float16)v.y, (_Float16)v.z, (_Float16)v.w};
    *(half4_t*)(xr + i) = h;
  }

  // conv weights + row pointers
  float wgt[25];
  #pragma unroll
  for (int q = 0; q < 25; q++) wgt[q] = lw[c * 25 + q];
  const float* xb = x + (size_t)b * HH * WW2 * CC + c;
  const float* rp[5];
  bool yv[5];
  #pragma unroll
  for (int ky = 0; ky < 5; ky++) {
    int yy = y + ky - 2;
    yv[ky] = (yy >= 0 && yy < HH);
    rp[ky] = xb + (size_t)(yv[ky] ? yy : 0) * WW2 * CC;
  }

  const _Float16* off_g = offA + ((size_t)b * 4096 + y * 64) * CC + c;
  size_t orow = (size_t)(b * HH + y) * WW2 * CC + c;

  // prefetch offsets for group 0 (u = 0..9 -> xi = -2..7; valid xi >= 0)
  float dxb[10];
  #pragma unroll
  for (int i = 2; i < 10; i++) dxb[i] = (float)off_g[(size_t)(i - 2) * CC];

  __syncthreads();

  float acc5[5] = {0.f, 0.f, 0.f, 0.f, 0.f};
  float asw = 0.f, acv = 0.f;

  for (int g = 0; g < 7; ++g) {
    #pragma unroll
    for (int uu = 0; uu < 10; ++uu) {
      int u = g * 10 + uu;
      acc5[(uu + 2) % 5] = 0.f;                 // slot for new output v=u+2
      if (u < 64) {
        float c0 = yv[0] ? rp[0][u * CC] : 0.f;
        float c1 = yv[1] ? rp[1][u * CC] : 0.f;
        float c2 = yv[2] ? rp[2][u * CC] : 0.f;
        float c3 = yv[3] ? rp[3][u * CC] : 0.f;
        float c4 = yv[4] ? rp[4][u * CC] : 0.f;
        #pragma unroll
        for (int kx = 0; kx < 5; kx++) {
          acc5[(uu + 7 - kx) % 5] += wgt[0 + kx] * c0 + wgt[5 + kx] * c1 +
                                     wgt[10 + kx] * c2 + wgt[15 + kx] * c3 +
                                     wgt[20 + kx] * c4;
        }
      }
      int xi = u - 2;
      if (xi >= 0 && xi < 64) {
        float dx = dxb[uu];
        float cv = acc5[(uu + 3) % 5];

        float xs = (float)xi + dx;
        float xf = floorf(xs);
        float wx = xs - xf;
        int xq = (int)xf;
        float v0 = (xq >= 0 && xq < WW2) ? (float)xr[xq * CC + c] : 0.f;
        float v1 = (xq + 1 >= 0 && xq + 1 < WW2) ? (float)xr[(xq + 1) * CC + c] : 0.f;
        float swv = (1.f - wx) * v0 + wx * v1;

        size_t oi = orow + (size_t)xi * CC;
        swb[oi] = (_Float16)swv;
        cvb[oi] = (_Float16)cv;
        asw += swv; acv += cv;
      }
    }
    // batch-prefetch next group's offsets (one alias-drain per 10 iters)
    if (g < 6) {
      #pragma unroll
      for (int uu = 0; uu < 10; ++uu) {
        int xi = (g + 1) * 10 + uu - 2;
        if (xi >= 0 && xi < 64) dxb[uu] = (float)off_g[(size_t)xi * CC];
      }
    }
  }

  atomicAdd(&ssw[b * CC + c], asw);
  atomicAdd(&scv[b * CC + c], acv);
}

// ---------------------------------------------------------------------------
// Kernel C: sh sampling. Block = (b, xi), thread = channel. x column staged
// f16 in LDS [y][c]; offsets read coalesced from offBT. No aliasing here
// (offBT/shb truly disjoint + restrict), so the compiler pipelines freely.
// ---------------------------------------------------------------------------
__global__ __launch_bounds__(256) void k_col(
    const float* __restrict__ x, const _Float16* __restrict__ offBT,
    _Float16* __restrict__ shb, float* __restrict__ ssh)
{
  __shared__ _Float16 xc[HH * CC];      // [y][c]
  const int work = (blockIdx.x & 7) * 128 + (blockIdx.x >> 3);  // 1024 blocks
  const int b = work >> 6, xi = work & 63;
  const int t = threadIdx.x;
  const int c = t;

  #pragma unroll
  for (int p = 0; p < 16; p++) {
    int yy = p * 4 + (t >> 6);
    int c4 = (t & 63) * 4;
    float4 v = *(const float4*)(x + ((size_t)(b * HH + yy) * WW2 + xi) * CC + c4);
    half4_t h = {(_Float16)v.x, (_Float16)v.y, (_Float16)v.z, (_Float16)v.w};
    *(half4_t*)(xc + yy * CC + c4) = h;
  }
  __syncthreads();

  const _Float16* obt = offBT + ((size_t)(b * WW2 + xi) * HH) * CC + c;
  float ash = 0.f;
  for (int yy = 0; yy < HH; yy++) {
    float dy = (float)obt[yy * CC];
    float ys = (float)yy + dy;
    float yf = floorf(ys);
    float wy = ys - yf;
    int yq = (int)yf;
    float u0 = (yq >= 0 && yq < HH) ? (float)xc[yq * CC + c] : 0.f;
    float u1 = (yq + 1 >= 0 && yq + 1 < HH) ? (float)xc[(yq + 1) * CC + c] : 0.f;
    float shv = (1.f - wy) * u0 + wy * u1;
    shb[((size_t)(b * HH + yy) * WW2 + xi) * CC + c] = (_Float16)shv;
    ash += shv;
  }
  atomicAdd(&ssh[b * CC + c], ash);
}

// ---------------------------------------------------------------------------
// Kernel B: gating MLP (validated).
// ---------------------------------------------------------------------------
__global__ __launch_bounds__(256) void k_gate(
    const float* __restrict__ ssw, const float* __restrict__ ssh, const float* __restrict__ scv,
    const float* __restrict__ Ww, const float* __restrict__ bw,
    const float* __restrict__ Wh, const float* __restrict__ bh,
    const float* __restrict__ blc,
    const float* __restrict__ fc1w, const float* __restrict__ fc1b,
    const float* __restrict__ fc2w, const float* __restrict__ fc2b,
    float* __restrict__ gate)
{
  __shared__ float sswl[CC], sshl[CC], avgl[CC], tl[64];
  const int b = blockIdx.x, tid = threadIdx.x;
  sswl[tid] = ssw[b * CC + tid];
  sshl[tid] = ssh[b * CC + tid];
  __syncthreads();

  float acc = scv[b * CC + tid];
  for (int c = 0; c < CC; c++)
    acc += sswl[c] * Ww[tid * CC + c] + sshl[c] * Wh[tid * CC + c];
  avgl[tid] = acc * (1.f / (HH * WW2)) + bw[tid] + bh[tid] + blc[tid];
  __syncthreads();

  if (tid < 64) {
    float a = fc1b[tid];
    for (int o = 0; o < CC; o++) a += avgl[o] * fc1w[tid * CC + o];
    tl[tid] = 0.5f * a * (1.f + erff(a * 0.70710678118654752f));
  }
  __syncthreads();

  float g[3];
  #pragma unroll
  for (int j = 0; j < 3; j++) {
    float a = fc2b[tid * 3 + j];
    for (int k = 0; k < 64; k++) a += tl[k] * fc2w[(tid * 3 + j) * 64 + k];
    g[j] = a;
  }
  float m = fmaxf(g[0], fmaxf(g[1], g[2]));
  float e0 = expf(g[0] - m), e1 = expf(g[1] - m), e2 = expf(g[2] - m);
  float inv = 1.f / (e0 + e1 + e2);
  gate[(0 * BB + b) * CC + tid] = e0 * inv;
  gate[(1 * BB + b) * CC + tid] = e1 * inv;
  gate[(2 * BB + b) * CC + tid] = e2 * inv;
}

// ---------------------------------------------------------------------------
// Kernel P: per-batch scaled concatenated weight B'[b][n][k] + combined bias.
// ---------------------------------------------------------------------------
__global__ __launch_bounds__(256) void k_prep(
    const float* __restrict__ gate,
    const float* __restrict__ Ww, const float* __restrict__ Wh,
    const float* __restrict__ bw, const float* __restrict__ bh,
    const float* __restrict__ blc,
    _Float16* __restrict__ Bp, float* __restrict__ bcomb)
{
  const int id = blockIdx.x;       // b*256 + n
  const int b = id >> 8, n = id & 255;
  const int k = threadIdx.x;
  float a0 = gate[(0 * BB + b) * CC + n];
  float a1 = gate[(1 * BB + b) * CC + n];
  float a2 = gate[(2 * BB + b) * CC + n];
  size_t base = (size_t)id * 512;
  Bp[base + k]       = (_Float16)(a0 * Ww[n * CC + k]);
  Bp[base + 256 + k] = (_Float16)(a1 * Wh[n * CC + k]);
  if (k == 0) bcomb[id] = a0 * bw[n] + a1 * bh[n] + a2 * blc[n];
}

__global__ __launch_bounds__(256) void k_cvt(const float* __restrict__ pw,
                                             _Float16* __restrict__ pf)
{
  int i = blockIdx.x * 256 + threadIdx.x;
  pf[i] = (_Float16)pw[i];
}

// ---------------------------------------------------------------------------
// Kernel F: FUSED gemm1+gemm2, 32-row tiles (grid 2048).
//   phase 1: comb = [sw|sh]@B'[b] + bcomb + a2*cv   (K=512) -> LDS f16
//   phase 2: out  = comb @ proj^T + proj_b          (K=256) -> f32 global
// acc[2][4] = 32 AGPR; __launch_bounds__(256,4) caps regs at 128 so we get
// 4 waves/SIMD (round-3 version was 180 regs -> 2 waves/SIMD -> 21% occ).
// ---------------------------------------------------------------------------
#define CPAD 260
__global__ __launch_bounds__(256, 4) void k_fused(
    const _Float16* __restrict__ swb, const _Float16* __restrict__ shb,
    const _Float16* __restrict__ Bp, const float* __restrict__ bcomb,
    const float* __restrict__ a2g, const _Float16* __restrict__ cvb,
    const _Float16* __restrict__ pf, const float* __restrict__ pb,
    float* __restrict__ out)
{
  __shared__ _Float16 comb[32 * CPAD];  // 16.6 KB

  const int work = (blockIdx.x & 7) * 256 + (blockIdx.x >> 3);  // 2048 blocks
  const int r0 = work * 32;
  const int b = work >> 7;              // 128 blocks per batch
  const int tid = threadIdx.x;
  const int wid = tid >> 6, l = tid & 63;
  const int n0 = wid * 64;
  const int lr = l & 15;
  const int kg = (l >> 4) * 8;
  const int jr = (l >> 4) * 4;

  // ---- phase 1: K=512 GEMM from global ----
  const _Float16* ap0 = swb + (size_t)(r0 + lr) * CC + kg;
  const _Float16* ap1 = shb + (size_t)(r0 + lr) * CC + kg;
  const _Float16* bp  = Bp + ((size_t)b * CC + n0 + lr) * 512 + kg;

  f32x4 acc[2][4];
  #pragma unroll
  for (int mi = 0; mi < 2; mi++)
    #pragma unroll
    for (int ni = 0; ni < 4; ni++) acc[mi][ni] = (f32x4){0.f, 0.f, 0.f, 0.f};

  #pragma unroll
  for (int ks = 0; ks < 16; ks++) {
    half8 a[2], bbv[4];
    #pragma unroll
    for (int mi = 0; mi < 2; mi++) {
      const _Float16* s = (ks < 8) ? (ap0 + (size_t)mi * 16 * CC + ks * 32)
                                   : (ap1 + (size_t)mi * 16 * CC + (ks - 8) * 32);
      a[mi] = *(const half8*)s;
    }
    #pragma unroll
    for (int ni = 0; ni < 4; ni++)
      bbv[ni] = *(const half8*)(bp + (size_t)ni * 16 * 512 + ks * 32);
    #pragma unroll
    for (int mi = 0; mi < 2; mi++)
      #pragma unroll
      for (int ni = 0; ni < 4; ni++)
        acc[mi][ni] = __builtin_amdgcn_mfma_f32_16x16x32_f16(a[mi], bbv[ni], acc[mi][ni], 0, 0, 0);
  }

  // epilogue 1: + bcomb + a2*cv, store comb tile to LDS
  #pragma unroll
  for (int ni = 0; ni < 4; ni++) {
    int col = n0 + ni * 16 + lr;
    float bc = bcomb[b * CC + col];
    float a2 = a2g[b * CC + col];
    #pragma unroll
    for (int mi = 0; mi < 2; mi++) {
      #pragma unroll
      for (int j = 0; j < 4; j++) {
        int r = mi * 16 + jr + j;
        size_t idx = (size_t)(r0 + r) * CC + col;
        float v = acc[mi][ni][j] + bc + a2 * (float)cvb[idx];
        comb[r * CPAD + col] = (_Float16)v;
      }
    }
  }
  __syncthreads();

  // ---- phase 2: K=256 GEMM, A from LDS, B = proj f16 from global ----
  const _Float16* bp2 = pf + (size_t)(n0 + lr) * CC + kg;

  f32x4 acc2[2][4];
  #pragma unroll
  for (int mi = 0; mi < 2; mi++)
    #pragma unroll
    for (int ni = 0; ni < 4; ni++) acc2[mi][ni] = (f32x4){0.f, 0.f, 0.f, 0.f};

  #pragma unroll
  for (int ks = 0; ks < 8; ks++) {
    half8 a[2], bbv[4];
    #pragma unroll
    for (int mi = 0; mi < 2; mi++) {
      const _Float16* s = comb + (mi * 16 + lr) * CPAD + kg + ks * 32;
      half4_t lo = *(const half4_t*)(s);
      half4_t hi = *(const half4_t*)(s + 4);
      a[mi][0] = lo[0]; a[mi][1] = lo[1]; a[mi][2] = lo[2]; a[mi][3] = lo[3];
      a[mi][4] = hi[0]; a[mi][5] = hi[1]; a[mi][6] = hi[2]; a[mi][7] = hi[3];
    }
    #pragma unroll
    for (int ni = 0; ni < 4; ni++)
      bbv[ni] = *(const half8*)(bp2 + (size_t)ni * 16 * CC + ks * 32);
    #pragma unroll
    for (int mi = 0; mi < 2; mi++)
      #pragma unroll
      for (int ni = 0; ni < 4; ni++)
        acc2[mi][ni] = __builtin_amdgcn_mfma_f32_16x16x32_f16(a[mi], bbv[ni], acc2[mi][ni], 0, 0, 0);
  }

  #pragma unroll
  for (int ni = 0; ni < 4; ni++) {
    int col = n0 + ni * 16 + lr;
    float bias = pb[col];
    #pragma unroll
    for (int mi = 0; mi < 2; mi++) {
      #pragma unroll
      for (int j = 0; j < 4; j++) {
        size_t idx = (size_t)(r0 + mi * 16 + jr + j) * CC + col;
        out[idx] = acc2[mi][ni][j] + bias;
      }
    }
  }
}

// ---------------------------------------------------------------------------
extern "C" void kernel_launch(void* const* d_in, const int* in_sizes, int n_in,
                              void* d_out, int out_size, void* d_ws, size_t ws_size,
                              hipStream_t stream)
{
  const float* x    = (const float*)d_in[0];
  const float* off  = (const float*)d_in[1];
  const float* Ww   = (const float*)d_in[2];
  const float* bw   = (const float*)d_in[3];
  const float* Wh   = (const float*)d_in[4];
  const float* bh   = (const float*)d_in[5];
  const float* lw   = (const float*)d_in[6];
  const float* blc  = (const float*)d_in[7];
  const float* fc1w = (const float*)d_in[8];
  const float* fc1b = (const float*)d_in[9];
  const float* fc2w = (const float*)d_in[10];
  const float* fc2b = (const float*)d_in[11];
  const float* pw   = (const float*)d_in[12];
  const float* pb   = (const float*)d_in[13];
  float* out = (float*)d_out;

  char* ws = (char*)d_ws;
  // workspace (peak ~100.3 MB):
  //   shb   @ 0     (32 MB)
  //   offAT @ 32 MB (32 MB)  -> aliased by swb  (k_row: per-elem read-then-write)
  //   offBT @ 64 MB (32 MB)  -> aliased by cvb  (offBT fully consumed by k_col first)
  //   Bp    @ 96 MB (4 MB); pf/sums/gate/bcomb after
  _Float16* shb   = (_Float16*)(ws + 0);
  _Float16* offAT = (_Float16*)(ws + 33554432);
  _Float16* swb   = (_Float16*)(ws + 33554432);   // alias of offAT
  _Float16* offBT = (_Float16*)(ws + 67108864);
  _Float16* cvb   = (_Float16*)(ws + 67108864);   // alias of offBT
  _Float16* Bp    = (_Float16*)(ws + 100663296);
  _Float16* pf    = (_Float16*)(ws + 104857600);
  float* sums     = (float*)(ws + 104988672);
  float* gate     = (float*)(ws + 105037824);
  float* bcomb    = (float*)(ws + 105086976);
  float* ssw = sums, *ssh = sums + 4096, *scv = sums + 8192;

  hipMemsetAsync(sums, 0, 3 * 4096 * sizeof(float), stream);
  k_trans<<<8192, 256, 0, stream>>>(off, offAT, offBT);
  k_col<<<BB * WW2, 256, 0, stream>>>(x, offBT, shb, ssh);
  k_row<<<BB * HH, 256, 0, stream>>>(x, offAT, lw, swb, cvb, ssw, scv);
  k_gate<<<BB, 256, 0, stream>>>(ssw, ssh, scv, Ww, bw, Wh, bh, blc,
                                 fc1w, fc1b, fc2w, fc2b, gate);
  k_prep<<<BB * CC, 256, 0, stream>>>(gate, Ww, Wh, bw, bh, blc, Bp, bcomb);
  k_cvt<<<CC, 256, 0, stream>>>(pw, pf);
  k_fused<<<2048, 256, 0, stream>>>(swb, shb, Bp, bcomb, gate + 2 * BB * CC,
                                    cvb, pf, pb, out);
}

// Round 6
// 306.028 us; speedup vs baseline: 1.1374x; 1.1374x over previous
//
#include <hip/hip_runtime.h>
#include <hip/hip_bf16.h>

typedef _Float16 half4_t __attribute__((ext_vector_type(4)));
typedef _Float16 half8 __attribute__((ext_vector_type(8)));
typedef float f32x4 __attribute__((ext_vector_type(4)));

#define BB 16
#define HH 64
#define WW2 64
#define CC 256

// ---------------------------------------------------------------------------
// Kernel T: LDS tile transpose of BOTH offset halves to pixel-major f16.
// (validated round 3: reads fully coalesced, writes 128B chunks, pad 65.)
// ---------------------------------------------------------------------------
__global__ __launch_bounds__(256) void k_trans(const float* __restrict__ off,
                                               _Float16* __restrict__ offAT,
                                               _Float16* __restrict__ offBT)
{
  __shared__ _Float16 tile[64][65];
  const int blk = blockIdx.x;          // b(16) * half(2) * cht(4) * st(64)
  const int st   = blk & 63;
  const int cht  = (blk >> 6) & 3;
  const int half = (blk >> 8) & 1;
  const int b    = blk >> 9;
  const int t = threadIdx.x;

  const int s0 = st * 64;
  const int ch0 = half * 256 + cht * 64;
  const float* src = off + ((size_t)b * 512 + ch0) * 4096 + s0;
  const int sl = t & 63;
  #pragma unroll
  for (int p = 0; p < 16; p++) {
    int chl = (t >> 6) + p * 4;
    tile[chl][sl] = (_Float16)src[(size_t)chl * 4096 + sl];
  }
  __syncthreads();

  _Float16* dst = (half == 0) ? offAT : offBT;
  #pragma unroll
  for (int p = 0; p < 2; p++) {
    int pl = (t >> 3) + p * 32;         // pixel within tile
    int c8 = (t & 7) * 8;
    half8 hv;
    #pragma unroll
    for (int r = 0; r < 8; r++) hv[r] = tile[c8 + r][pl];
    int s = s0 + pl;
    size_t pix = (half == 0) ? ((size_t)b * 4096 + s)
                             : ((size_t)b * 4096 + (s & 63) * 64 + (s >> 6));
    *(half8*)(dst + pix * 256 + cht * 64 + c8) = hv;
  }
}

// ---------------------------------------------------------------------------
// Kernel RS: sw sampling ONLY. Block = (b,y), thread = channel. All buffers
// truly disjoint (__restrict__ honest) -> compiler pipelines the whole loop.
// Tiny register footprint, no spills.
// ---------------------------------------------------------------------------
__global__ __launch_bounds__(256) void k_rows(
    const float* __restrict__ x, const _Float16* __restrict__ offA,
    _Float16* __restrict__ swb, float* __restrict__ ssw)
{
  __shared__ _Float16 xr[WW2 * CC];     // [xi][c], 32 KB

  const int work = (blockIdx.x & 7) * 128 + (blockIdx.x >> 3);  // 1024 blocks
  const int b = work >> 6, y = work & 63;
  const int t = threadIdx.x;
  const int c = t;

  const float* xrow_src = x + (size_t)(b * HH + y) * WW2 * CC;
  #pragma unroll
  for (int p = 0; p < 16; p++) {
    int i = p * 1024 + t * 4;
    float4 v = *(const float4*)(xrow_src + i);
    half4_t h = {(_Float16)v.x, (_Float16)v.y, (_Float16)v.z, (_Float16)v.w};
    *(half4_t*)(xr + i) = h;
  }
  __syncthreads();

  const _Float16* op = offA + ((size_t)b * 4096 + y * 64) * CC + c;
  _Float16* sp = swb + ((size_t)b * 4096 + y * 64) * CC + c;
  float asw = 0.f;

  #pragma unroll 8
  for (int xi = 0; xi < 64; xi++) {
    float dx = (float)op[(size_t)xi * CC];
    float xs = (float)xi + dx;
    float xf = floorf(xs);
    float wx = xs - xf;
    int xq = (int)xf;
    float v0 = (xq >= 0 && xq < WW2) ? (float)xr[xq * CC + c] : 0.f;
    float v1 = (xq + 1 >= 0 && xq + 1 < WW2) ? (float)xr[(xq + 1) * CC + c] : 0.f;
    float swv = (1.f - wx) * v0 + wx * v1;
    sp[(size_t)xi * CC] = (_Float16)swv;
    asw += swv;
  }
  atomicAdd(&ssw[b * CC + c], asw);
}

// ---------------------------------------------------------------------------
// Kernel V: depthwise 5x5 conv ONLY. Block = (b,y), thread = channel.
// No LDS (x rows via L1/L2, reused by 5 adjacent y-blocks on same XCD).
// 5-accumulator column ring (validated math from round 3), static indices.
// Register need ~50 -> no spills, 8 waves/SIMD possible.
// ---------------------------------------------------------------------------
__global__ __launch_bounds__(256) void k_conv(
    const float* __restrict__ x, const float* __restrict__ lw,
    _Float16* __restrict__ cvb, float* __restrict__ scv)
{
  const int work = (blockIdx.x & 7) * 128 + (blockIdx.x >> 3);  // 1024 blocks
  const int b = work >> 6, y = work & 63;
  const int c = threadIdx.x;

  float wgt[25];
  #pragma unroll
  for (int q = 0; q < 25; q++) wgt[q] = lw[c * 25 + q];

  const float* xb = x + (size_t)b * HH * WW2 * CC + c;
  const float* rp[5];
  bool yv[5];
  #pragma unroll
  for (int ky = 0; ky < 5; ky++) {
    int yy = y + ky - 2;
    yv[ky] = (yy >= 0 && yy < HH);
    rp[ky] = xb + (size_t)(yv[ky] ? yy : 0) * WW2 * CC;
  }

  _Float16* cp = cvb + ((size_t)b * 4096 + y * 64) * CC + c;
  float acc5[5] = {0.f, 0.f, 0.f, 0.f, 0.f};
  float acv = 0.f;

  #pragma unroll 5
  for (int u = 0; u < 70; ++u) {
    acc5[(u + 2) % 5] = 0.f;                 // slot for new output v=u+2
    if (u < 64) {
      float c0 = yv[0] ? rp[0][u * CC] : 0.f;
      float c1 = yv[1] ? rp[1][u * CC] : 0.f;
      float c2 = yv[2] ? rp[2][u * CC] : 0.f;
      float c3 = yv[3] ? rp[3][u * CC] : 0.f;
      float c4 = yv[4] ? rp[4][u * CC] : 0.f;
      #pragma unroll
      for (int kx = 0; kx < 5; kx++) {
        acc5[(u + 7 - kx) % 5] += wgt[0 + kx] * c0 + wgt[5 + kx] * c1 +
                                  wgt[10 + kx] * c2 + wgt[15 + kx] * c3 +
                                  wgt[20 + kx] * c4;
      }
    }
    int xi = u - 2;
    if (xi >= 0 && xi < 64) {
      float cv = acc5[(u + 3) % 5];
      cp[(size_t)xi * CC] = (_Float16)cv;
      acv += cv;
    }
  }
  atomicAdd(&scv[b * CC + c], acv);
}

// ---------------------------------------------------------------------------
// Kernel C: sh sampling. Block = (b, xi), thread = channel. x column staged
// f16 in LDS [y][c]; offsets read coalesced from offBT. All disjoint.
// ---------------------------------------------------------------------------
__global__ __launch_bounds__(256) void k_col(
    const float* __restrict__ x, const _Float16* __restrict__ offBT,
    _Float16* __restrict__ shb, float* __restrict__ ssh)
{
  __shared__ _Float16 xc[HH * CC];      // [y][c]
  const int work = (blockIdx.x & 7) * 128 + (blockIdx.x >> 3);  // 1024 blocks
  const int b = work >> 6, xi = work & 63;
  const int t = threadIdx.x;
  const int c = t;

  #pragma unroll
  for (int p = 0; p < 16; p++) {
    int yy = p * 4 + (t >> 6);
    int c4 = (t & 63) * 4;
    float4 v = *(const float4*)(x + ((size_t)(b * HH + yy) * WW2 + xi) * CC + c4);
    half4_t h = {(_Float16)v.x, (_Float16)v.y, (_Float16)v.z, (_Float16)v.w};
    *(half4_t*)(xc + yy * CC + c4) = h;
  }
  __syncthreads();

  const _Float16* obt = offBT + ((size_t)(b * WW2 + xi) * HH) * CC + c;
  _Float16* hp = shb + ((size_t)(b * HH) * WW2 + xi) * CC + c;
  float ash = 0.f;
  #pragma unroll 8
  for (int yy = 0; yy < 64; yy++) {
    float dy = (float)obt[(size_t)yy * CC];
    float ys = (float)yy + dy;
    float yf = floorf(ys);
    float wy = ys - yf;
    int yq = (int)yf;
    float u0 = (yq >= 0 && yq < HH) ? (float)xc[yq * CC + c] : 0.f;
    float u1 = (yq + 1 >= 0 && yq + 1 < HH) ? (float)xc[(yq + 1) * CC + c] : 0.f;
    float shv = (1.f - wy) * u0 + wy * u1;
    hp[(size_t)yy * WW2 * CC] = (_Float16)shv;
    ash += shv;
  }
  atomicAdd(&ssh[b * CC + c], ash);
}

// ---------------------------------------------------------------------------
// Kernel B: gating MLP (validated).
// ---------------------------------------------------------------------------
__global__ __launch_bounds__(256) void k_gate(
    const float* __restrict__ ssw, const float* __restrict__ ssh, const float* __restrict__ scv,
    const float* __restrict__ Ww, const float* __restrict__ bw,
    const float* __restrict__ Wh, const float* __restrict__ bh,
    const float* __restrict__ blc,
    const float* __restrict__ fc1w, const float* __restrict__ fc1b,
    const float* __restrict__ fc2w, const float* __restrict__ fc2b,
    float* __restrict__ gate)
{
  __shared__ float sswl[CC], sshl[CC], avgl[CC], tl[64];
  const int b = blockIdx.x, tid = threadIdx.x;
  sswl[tid] = ssw[b * CC + tid];
  sshl[tid] = ssh[b * CC + tid];
  __syncthreads();

  float acc = scv[b * CC + tid];
  for (int c = 0; c < CC; c++)
    acc += sswl[c] * Ww[tid * CC + c] + sshl[c] * Wh[tid * CC + c];
  avgl[tid] = acc * (1.f / (HH * WW2)) + bw[tid] + bh[tid] + blc[tid];
  __syncthreads();

  if (tid < 64) {
    float a = fc1b[tid];
    for (int o = 0; o < CC; o++) a += avgl[o] * fc1w[tid * CC + o];
    tl[tid] = 0.5f * a * (1.f + erff(a * 0.70710678118654752f));
  }
  __syncthreads();

  float g[3];
  #pragma unroll
  for (int j = 0; j < 3; j++) {
    float a = fc2b[tid * 3 + j];
    for (int k = 0; k < 64; k++) a += tl[k] * fc2w[(tid * 3 + j) * 64 + k];
    g[j] = a;
  }
  float m = fmaxf(g[0], fmaxf(g[1], g[2]));
  float e0 = expf(g[0] - m), e1 = expf(g[1] - m), e2 = expf(g[2] - m);
  float inv = 1.f / (e0 + e1 + e2);
  gate[(0 * BB + b) * CC + tid] = e0 * inv;
  gate[(1 * BB + b) * CC + tid] = e1 * inv;
  gate[(2 * BB + b) * CC + tid] = e2 * inv;
}

// ---------------------------------------------------------------------------
// Kernel P: per-batch scaled concatenated weight B'[b][n][k] + combined bias.
// ---------------------------------------------------------------------------
__global__ __launch_bounds__(256) void k_prep(
    const float* __restrict__ gate,
    const float* __restrict__ Ww, const float* __restrict__ Wh,
    const float* __restrict__ bw, const float* __restrict__ bh,
    const float* __restrict__ blc,
    _Float16* __restrict__ Bp, float* __restrict__ bcomb)
{
  const int id = blockIdx.x;       // b*256 + n
  const int b = id >> 8, n = id & 255;
  const int k = threadIdx.x;
  float a0 = gate[(0 * BB + b) * CC + n];
  float a1 = gate[(1 * BB + b) * CC + n];
  float a2 = gate[(2 * BB + b) * CC + n];
  size_t base = (size_t)id * 512;
  Bp[base + k]       = (_Float16)(a0 * Ww[n * CC + k]);
  Bp[base + 256 + k] = (_Float16)(a1 * Wh[n * CC + k]);
  if (k == 0) bcomb[id] = a0 * bw[n] + a1 * bh[n] + a2 * blc[n];
}

__global__ __launch_bounds__(256) void k_cvt(const float* __restrict__ pw,
                                             _Float16* __restrict__ pf)
{
  int i = blockIdx.x * 256 + threadIdx.x;
  pf[i] = (_Float16)pw[i];
}

// ---------------------------------------------------------------------------
// Kernel F: FUSED gemm1+gemm2 (round-3 validated shape: 64-row tiles,
// acc[4][4], no min-waves cap -> compiler keeps ILP registers).
//   phase 1: comb = [sw|sh]@B'[b] + bcomb + a2*cv   (K=512) -> LDS f16
//   phase 2: out  = comb @ proj^T + proj_b          (K=256) -> f32 global
// ---------------------------------------------------------------------------
#define CPAD 260
__global__ __launch_bounds__(256) void k_fused(
    const _Float16* __restrict__ swb, const _Float16* __restrict__ shb,
    const _Float16* __restrict__ Bp, const float* __restrict__ bcomb,
    const float* __restrict__ a2g, const _Float16* __restrict__ cvb,
    const _Float16* __restrict__ pf, const float* __restrict__ pb,
    float* __restrict__ out)
{
  __shared__ _Float16 comb[64 * CPAD];  // 32.5 KB

  const int work = (blockIdx.x & 7) * 128 + (blockIdx.x >> 3);  // 1024 blocks
  const int r0 = work * 64;
  const int b = work >> 6;
  const int tid = threadIdx.x;
  const int wid = tid >> 6, l = tid & 63;
  const int n0 = wid * 64;
  const int lr = l & 15;
  const int kg = (l >> 4) * 8;
  const int jr = (l >> 4) * 4;

  // ---- phase 1: K=512 GEMM from global ----
  const _Float16* ap0 = swb + (size_t)(r0 + lr) * CC + kg;
  const _Float16* ap1 = shb + (size_t)(r0 + lr) * CC + kg;
  const _Float16* bp  = Bp + ((size_t)b * CC + n0 + lr) * 512 + kg;

  f32x4 acc[4][4];
  #pragma unroll
  for (int mi = 0; mi < 4; mi++)
    #pragma unroll
    for (int ni = 0; ni < 4; ni++) acc[mi][ni] = (f32x4){0.f, 0.f, 0.f, 0.f};

  #pragma unroll
  for (int ks = 0; ks < 16; ks++) {
    half8 a[4], bbv[4];
    #pragma unroll
    for (int mi = 0; mi < 4; mi++) {
      const _Float16* s = (ks < 8) ? (ap0 + (size_t)mi * 16 * CC + ks * 32)
                                   : (ap1 + (size_t)mi * 16 * CC + (ks - 8) * 32);
      a[mi] = *(const half8*)s;
    }
    #pragma unroll
    for (int ni = 0; ni < 4; ni++)
      bbv[ni] = *(const half8*)(bp + (size_t)ni * 16 * 512 + ks * 32);
    #pragma unroll
    for (int mi = 0; mi < 4; mi++)
      #pragma unroll
      for (int ni = 0; ni < 4; ni++)
        acc[mi][ni] = __builtin_amdgcn_mfma_f32_16x16x32_f16(a[mi], bbv[ni], acc[mi][ni], 0, 0, 0);
  }

  // epilogue 1: + bcomb + a2*cv, store comb tile to LDS
  #pragma unroll
  for (int ni = 0; ni < 4; ni++) {
    int col = n0 + ni * 16 + lr;
    float bc = bcomb[b * CC + col];
    float a2 = a2g[b * CC + col];
    #pragma unroll
    for (int mi = 0; mi < 4; mi++) {
      #pragma unroll
      for (int j = 0; j < 4; j++) {
        int r = mi * 16 + jr + j;
        size_t idx = (size_t)(r0 + r) * CC + col;
        float v = acc[mi][ni][j] + bc + a2 * (float)cvb[idx];
        comb[r * CPAD + col] = (_Float16)v;
      }
    }
  }
  __syncthreads();

  // ---- phase 2: K=256 GEMM, A from LDS, B = proj f16 from global ----
  const _Float16* bp2 = pf + (size_t)(n0 + lr) * CC + kg;

  f32x4 acc2[4][4];
  #pragma unroll
  for (int mi = 0; mi < 4; mi++)
    #pragma unroll
    for (int ni = 0; ni < 4; ni++) acc2[mi][ni] = (f32x4){0.f, 0.f, 0.f, 0.f};

  #pragma unroll
  for (int ks = 0; ks < 8; ks++) {
    half8 a[4], bbv[4];
    #pragma unroll
    for (int mi = 0; mi < 4; mi++) {
      const _Float16* s = comb + (mi * 16 + lr) * CPAD + kg + ks * 32;
      half4_t lo = *(const half4_t*)(s);
      half4_t hi = *(const half4_t*)(s + 4);
      a[mi][0] = lo[0]; a[mi][1] = lo[1]; a[mi][2] = lo[2]; a[mi][3] = lo[3];
      a[mi][4] = hi[0]; a[mi][5] = hi[1]; a[mi][6] = hi[2]; a[mi][7] = hi[3];
    }
    #pragma unroll
    for (int ni = 0; ni < 4; ni++)
      bbv[ni] = *(const half8*)(bp2 + (size_t)ni * 16 * CC + ks * 32);
    #pragma unroll
    for (int mi = 0; mi < 4; mi++)
      #pragma unroll
      for (int ni = 0; ni < 4; ni++)
        acc2[mi][ni] = __builtin_amdgcn_mfma_f32_16x16x32_f16(a[mi], bbv[ni], acc2[mi][ni], 0, 0, 0);
  }

  #pragma unroll
  for (int ni = 0; ni < 4; ni++) {
    int col = n0 + ni * 16 + lr;
    float bias = pb[col];
    #pragma unroll
    for (int mi = 0; mi < 4; mi++) {
      #pragma unroll
      for (int j = 0; j < 4; j++) {
        size_t idx = (size_t)(r0 + mi * 16 + jr + j) * CC + col;
        out[idx] = acc2[mi][ni][j] + bias;
      }
    }
  }
}

// ---------------------------------------------------------------------------
extern "C" void kernel_launch(void* const* d_in, const int* in_sizes, int n_in,
                              void* d_out, int out_size, void* d_ws, size_t ws_size,
                              hipStream_t stream)
{
  const float* x    = (const float*)d_in[0];
  const float* off  = (const float*)d_in[1];
  const float* Ww   = (const float*)d_in[2];
  const float* bw   = (const float*)d_in[3];
  const float* Wh   = (const float*)d_in[4];
  const float* bh   = (const float*)d_in[5];
  const float* lw   = (const float*)d_in[6];
  const float* blc  = (const float*)d_in[7];
  const float* fc1w = (const float*)d_in[8];
  const float* fc1b = (const float*)d_in[9];
  const float* fc2w = (const float*)d_in[10];
  const float* fc2b = (const float*)d_in[11];
  const float* pw   = (const float*)d_in[12];
  const float* pb   = (const float*)d_in[13];
  float* out = (float*)d_out;

  char* ws = (char*)d_ws;
  // workspace (peak ~100.3 MB), NO concurrent aliasing (buffer-role rotation):
  //   R0 @ 0    : shb   (k_col writes)
  //   R1 @ 32MB : offAT (k_trans->k_rows reads), THEN cvb (k_conv writes after)
  //   R2 @ 64MB : offBT (k_trans->k_col reads), THEN swb (k_rows writes after)
  //   Bp @ 96MB (4MB); pf/sums/gate/bcomb after
  _Float16* shb   = (_Float16*)(ws + 0);
  _Float16* offAT = (_Float16*)(ws + 33554432);
  _Float16* cvb   = (_Float16*)(ws + 33554432);   // reuses R1 after k_rows
  _Float16* offBT = (_Float16*)(ws + 67108864);
  _Float16* swb   = (_Float16*)(ws + 67108864);   // reuses R2 after k_col
  _Float16* Bp    = (_Float16*)(ws + 100663296);
  _Float16* pf    = (_Float16*)(ws + 104857600);
  float* sums     = (float*)(ws + 104988672);
  float* gate     = (float*)(ws + 105037824);
  float* bcomb    = (float*)(ws + 105086976);
  float* ssw = sums, *ssh = sums + 4096, *scv = sums + 8192;

  hipMemsetAsync(sums, 0, 3 * 4096 * sizeof(float), stream);
  k_trans<<<8192, 256, 0, stream>>>(off, offAT, offBT);
  k_col<<<BB * WW2, 256, 0, stream>>>(x, offBT, shb, ssh);     // consumes offBT
  k_rows<<<BB * HH, 256, 0, stream>>>(x, offAT, swb, ssw);     // consumes offAT, writes R2
  k_conv<<<BB * HH, 256, 0, stream>>>(x, lw, cvb, scv);        // writes R1
  k_gate<<<BB, 256, 0, stream>>>(ssw, ssh, scv, Ww, bw, Wh, bh, blc,
                                 fc1w, fc1b, fc2w, fc2b, gate);
  k_prep<<<BB * CC, 256, 0, stream>>>(gate, Ww, Wh, bw, bh, blc, Bp, bcomb);
  k_cvt<<<CC, 256, 0, stream>>>(pw, pf);
  k_fused<<<1024, 256, 0, stream>>>(swb, shb, Bp, bcomb, gate + 2 * BB * CC,
                                    cvb, pf, pb, out);
}

// Round 7
// 293.793 us; speedup vs baseline: 1.1847x; 1.0416x over previous
//
#include <hip/hip_runtime.h>
#include <hip/hip_bf16.h>

typedef _Float16 half4_t __attribute__((ext_vector_type(4)));
typedef _Float16 half8 __attribute__((ext_vector_type(8)));
typedef float f32x4 __attribute__((ext_vector_type(4)));

#define BB 16
#define HH 64
#define WW2 64
#define CC 256

// ---------------------------------------------------------------------------
// Kernel T: LDS tile transpose of BOTH offset halves to pixel-major f16.
// (validated round 3: reads fully coalesced, writes 128B chunks, pad 65.)
// ---------------------------------------------------------------------------
__global__ __launch_bounds__(256) void k_trans(const float* __restrict__ off,
                                               _Float16* __restrict__ offAT,
                                               _Float16* __restrict__ offBT)
{
  __shared__ _Float16 tile[64][65];
  const int blk = blockIdx.x;          // b(16) * half(2) * cht(4) * st(64)
  const int st   = blk & 63;
  const int cht  = (blk >> 6) & 3;
  const int half = (blk >> 8) & 1;
  const int b    = blk >> 9;
  const int t = threadIdx.x;

  const int s0 = st * 64;
  const int ch0 = half * 256 + cht * 64;
  const float* src = off + ((size_t)b * 512 + ch0) * 4096 + s0;
  const int sl = t & 63;
  #pragma unroll
  for (int p = 0; p < 16; p++) {
    int chl = (t >> 6) + p * 4;
    tile[chl][sl] = (_Float16)src[(size_t)chl * 4096 + sl];
  }
  __syncthreads();

  _Float16* dst = (half == 0) ? offAT : offBT;
  #pragma unroll
  for (int p = 0; p < 2; p++) {
    int pl = (t >> 3) + p * 32;         // pixel within tile
    int c8 = (t & 7) * 8;
    half8 hv;
    #pragma unroll
    for (int r = 0; r < 8; r++) hv[r] = tile[c8 + r][pl];
    int s = s0 + pl;
    size_t pix = (half == 0) ? ((size_t)b * 4096 + s)
                             : ((size_t)b * 4096 + (s & 63) * 64 + (s >> 6));
    *(half8*)(dst + pix * 256 + cht * 64 + c8) = hv;
  }
}

// ---------------------------------------------------------------------------
// Kernel RS: sw sampling ONLY (validated round 5).
// ---------------------------------------------------------------------------
__global__ __launch_bounds__(256) void k_rows(
    const float* __restrict__ x, const _Float16* __restrict__ offA,
    _Float16* __restrict__ swb, float* __restrict__ ssw)
{
  __shared__ _Float16 xr[WW2 * CC];     // [xi][c], 32 KB

  const int work = (blockIdx.x & 7) * 128 + (blockIdx.x >> 3);  // 1024 blocks
  const int b = work >> 6, y = work & 63;
  const int t = threadIdx.x;
  const int c = t;

  const float* xrow_src = x + (size_t)(b * HH + y) * WW2 * CC;
  #pragma unroll
  for (int p = 0; p < 16; p++) {
    int i = p * 1024 + t * 4;
    float4 v = *(const float4*)(xrow_src + i);
    half4_t h = {(_Float16)v.x, (_Float16)v.y, (_Float16)v.z, (_Float16)v.w};
    *(half4_t*)(xr + i) = h;
  }
  __syncthreads();

  const _Float16* op = offA + ((size_t)b * 4096 + y * 64) * CC + c;
  _Float16* sp = swb + ((size_t)b * 4096 + y * 64) * CC + c;
  float asw = 0.f;

  #pragma unroll 8
  for (int xi = 0; xi < 64; xi++) {
    float dx = (float)op[(size_t)xi * CC];
    float xs = (float)xi + dx;
    float xf = floorf(xs);
    float wx = xs - xf;
    int xq = (int)xf;
    float v0 = (xq >= 0 && xq < WW2) ? (float)xr[xq * CC + c] : 0.f;
    float v1 = (xq + 1 >= 0 && xq + 1 < WW2) ? (float)xr[(xq + 1) * CC + c] : 0.f;
    float swv = (1.f - wx) * v0 + wx * v1;
    sp[(size_t)xi * CC] = (_Float16)swv;
    asw += swv;
  }
  atomicAdd(&ssw[b * CC + c], asw);
}

// ---------------------------------------------------------------------------
// Kernel V: depthwise 5x5 conv ONLY (validated round 5).
// ---------------------------------------------------------------------------
__global__ __launch_bounds__(256) void k_conv(
    const float* __restrict__ x, const float* __restrict__ lw,
    _Float16* __restrict__ cvb, float* __restrict__ scv)
{
  const int work = (blockIdx.x & 7) * 128 + (blockIdx.x >> 3);  // 1024 blocks
  const int b = work >> 6, y = work & 63;
  const int c = threadIdx.x;

  float wgt[25];
  #pragma unroll
  for (int q = 0; q < 25; q++) wgt[q] = lw[c * 25 + q];

  const float* xb = x + (size_t)b * HH * WW2 * CC + c;
  const float* rp[5];
  bool yv[5];
  #pragma unroll
  for (int ky = 0; ky < 5; ky++) {
    int yy = y + ky - 2;
    yv[ky] = (yy >= 0 && yy < HH);
    rp[ky] = xb + (size_t)(yv[ky] ? yy : 0) * WW2 * CC;
  }

  _Float16* cp = cvb + ((size_t)b * 4096 + y * 64) * CC + c;
  float acc5[5] = {0.f, 0.f, 0.f, 0.f, 0.f};
  float acv = 0.f;

  #pragma unroll 5
  for (int u = 0; u < 70; ++u) {
    acc5[(u + 2) % 5] = 0.f;                 // slot for new output v=u+2
    if (u < 64) {
      float c0 = yv[0] ? rp[0][u * CC] : 0.f;
      float c1 = yv[1] ? rp[1][u * CC] : 0.f;
      float c2 = yv[2] ? rp[2][u * CC] : 0.f;
      float c3 = yv[3] ? rp[3][u * CC] : 0.f;
      float c4 = yv[4] ? rp[4][u * CC] : 0.f;
      #pragma unroll
      for (int kx = 0; kx < 5; kx++) {
        acc5[(u + 7 - kx) % 5] += wgt[0 + kx] * c0 + wgt[5 + kx] * c1 +
                                  wgt[10 + kx] * c2 + wgt[15 + kx] * c3 +
                                  wgt[20 + kx] * c4;
      }
    }
    int xi = u - 2;
    if (xi >= 0 && xi < 64) {
      float cv = acc5[(u + 3) % 5];
      cp[(size_t)xi * CC] = (_Float16)cv;
      acv += cv;
    }
  }
  atomicAdd(&scv[b * CC + c], acv);
}

// ---------------------------------------------------------------------------
// Kernel C: sh sampling (validated round 5).
// ---------------------------------------------------------------------------
__global__ __launch_bounds__(256) void k_col(
    const float* __restrict__ x, const _Float16* __restrict__ offBT,
    _Float16* __restrict__ shb, float* __restrict__ ssh)
{
  __shared__ _Float16 xc[HH * CC];      // [y][c]
  const int work = (blockIdx.x & 7) * 128 + (blockIdx.x >> 3);  // 1024 blocks
  const int b = work >> 6, xi = work & 63;
  const int t = threadIdx.x;
  const int c = t;

  #pragma unroll
  for (int p = 0; p < 16; p++) {
    int yy = p * 4 + (t >> 6);
    int c4 = (t & 63) * 4;
    float4 v = *(const float4*)(x + ((size_t)(b * HH + yy) * WW2 + xi) * CC + c4);
    half4_t h = {(_Float16)v.x, (_Float16)v.y, (_Float16)v.z, (_Float16)v.w};
    *(half4_t*)(xc + yy * CC + c4) = h;
  }
  __syncthreads();

  const _Float16* obt = offBT + ((size_t)(b * WW2 + xi) * HH) * CC + c;
  _Float16* hp = shb + ((size_t)(b * HH) * WW2 + xi) * CC + c;
  float ash = 0.f;
  #pragma unroll 8
  for (int yy = 0; yy < 64; yy++) {
    float dy = (float)obt[(size_t)yy * CC];
    float ys = (float)yy + dy;
    float yf = floorf(ys);
    float wy = ys - yf;
    int yq = (int)yf;
    float u0 = (yq >= 0 && yq < HH) ? (float)xc[yq * CC + c] : 0.f;
    float u1 = (yq + 1 >= 0 && yq + 1 < HH) ? (float)xc[(yq + 1) * CC + c] : 0.f;
    float shv = (1.f - wy) * u0 + wy * u1;
    hp[(size_t)yy * WW2 * CC] = (_Float16)shv;
    ash += shv;
  }
  atomicAdd(&ssh[b * CC + c], ash);
}

// ---------------------------------------------------------------------------
// Kernel B: gating MLP (validated).
// ---------------------------------------------------------------------------
__global__ __launch_bounds__(256) void k_gate(
    const float* __restrict__ ssw, const float* __restrict__ ssh, const float* __restrict__ scv,
    const float* __restrict__ Ww, const float* __restrict__ bw,
    const float* __restrict__ Wh, const float* __restrict__ bh,
    const float* __restrict__ blc,
    const float* __restrict__ fc1w, const float* __restrict__ fc1b,
    const float* __restrict__ fc2w, const float* __restrict__ fc2b,
    float* __restrict__ gate)
{
  __shared__ float sswl[CC], sshl[CC], avgl[CC], tl[64];
  const int b = blockIdx.x, tid = threadIdx.x;
  sswl[tid] = ssw[b * CC + tid];
  sshl[tid] = ssh[b * CC + tid];
  __syncthreads();

  float acc = scv[b * CC + tid];
  for (int c = 0; c < CC; c++)
    acc += sswl[c] * Ww[tid * CC + c] + sshl[c] * Wh[tid * CC + c];
  avgl[tid] = acc * (1.f / (HH * WW2)) + bw[tid] + bh[tid] + blc[tid];
  __syncthreads();

  if (tid < 64) {
    float a = fc1b[tid];
    for (int o = 0; o < CC; o++) a += avgl[o] * fc1w[tid * CC + o];
    tl[tid] = 0.5f * a * (1.f + erff(a * 0.70710678118654752f));
  }
  __syncthreads();

  float g[3];
  #pragma unroll
  for (int j = 0; j < 3; j++) {
    float a = fc2b[tid * 3 + j];
    for (int k = 0; k < 64; k++) a += tl[k] * fc2w[(tid * 3 + j) * 64 + k];
    g[j] = a;
  }
  float m = fmaxf(g[0], fmaxf(g[1], g[2]));
  float e0 = expf(g[0] - m), e1 = expf(g[1] - m), e2 = expf(g[2] - m);
  float inv = 1.f / (e0 + e1 + e2);
  gate[(0 * BB + b) * CC + tid] = e0 * inv;
  gate[(1 * BB + b) * CC + tid] = e1 * inv;
  gate[(2 * BB + b) * CC + tid] = e2 * inv;
}

// ---------------------------------------------------------------------------
// Kernel P: per-batch scaled concatenated weight B'[b][n][k] + combined bias.
// ---------------------------------------------------------------------------
__global__ __launch_bounds__(256) void k_prep(
    const float* __restrict__ gate,
    const float* __restrict__ Ww, const float* __restrict__ Wh,
    const float* __restrict__ bw, const float* __restrict__ bh,
    const float* __restrict__ blc,
    _Float16* __restrict__ Bp, float* __restrict__ bcomb)
{
  const int id = blockIdx.x;       // b*256 + n
  const int b = id >> 8, n = id & 255;
  const int k = threadIdx.x;
  float a0 = gate[(0 * BB + b) * CC + n];
  float a1 = gate[(1 * BB + b) * CC + n];
  float a2 = gate[(2 * BB + b) * CC + n];
  size_t base = (size_t)id * 512;
  Bp[base + k]       = (_Float16)(a0 * Ww[n * CC + k]);
  Bp[base + 256 + k] = (_Float16)(a1 * Wh[n * CC + k]);
  if (k == 0) bcomb[id] = a0 * bw[n] + a1 * bh[n] + a2 * blc[n];
}

__global__ __launch_bounds__(256) void k_cvt(const float* __restrict__ pw,
                                             _Float16* __restrict__ pf)
{
  int i = blockIdx.x * 256 + threadIdx.x;
  pf[i] = (_Float16)pw[i];
}

// ---------------------------------------------------------------------------
// Kernel F: FUSED gemm1+gemm2 with LDS-staged A.
//   stage : A0 = swb rows[r0..r0+63] (32KB contiguous), A1 = shb rows (32KB)
//           -> LDS [64][APAD] f16, coalesced half8 loads (A read ONCE, not 4x)
//   phase 1: comb = [A0|A1]@B'[b] + bcomb + a2*cv   (K=512, A via ds_read_b128)
//   phase 2: out  = comb @ proj^T + proj_b          (K=256, comb in LDS)
// APAD=264: b128 row reads hit 8 distinct 16B bank-slots = b128 minimum (free).
// comb reuses the A0 region after a barrier (CPAD 260, validated).
// ---------------------------------------------------------------------------
#define APAD 264
#define CPAD 260
__global__ __launch_bounds__(256) void k_fused(
    const _Float16* __restrict__ swb, const _Float16* __restrict__ shb,
    const _Float16* __restrict__ Bp, const float* __restrict__ bcomb,
    const float* __restrict__ a2g, const _Float16* __restrict__ cvb,
    const _Float16* __restrict__ pf, const float* __restrict__ pb,
    float* __restrict__ out)
{
  __shared__ _Float16 smem[2 * 64 * APAD];  // 66 KB; comb aliases front

  const int work = (blockIdx.x & 7) * 128 + (blockIdx.x >> 3);  // 1024 blocks
  const int r0 = work * 64;
  const int b = work >> 6;
  const int tid = threadIdx.x;
  const int wid = tid >> 6, l = tid & 63;
  const int n0 = wid * 64;
  const int lr = l & 15;
  const int kg = (l >> 4) * 8;
  const int jr = (l >> 4) * 4;

  // ---- stage A tiles (each a contiguous 32KB global block) ----
  {
    const _Float16* gsw = swb + (size_t)r0 * CC;
    const _Float16* gsh = shb + (size_t)r0 * CC;
    #pragma unroll
    for (int p = 0; p < 8; p++) {
      int i = p * 2048 + tid * 8;          // f16 linear index in [64*256)
      int row = i >> 8, colp = i & 255;
      half8 v0 = *(const half8*)(gsw + i);
      half8 v1 = *(const half8*)(gsh + i);
      *(half8*)(smem + row * APAD + colp) = v0;
      *(half8*)(smem + 64 * APAD + row * APAD + colp) = v1;
    }
  }
  __syncthreads();

  // ---- phase 1: K=512 GEMM, A from LDS, B' from global (L2-resident) ----
  const _Float16* bp = Bp + ((size_t)b * CC + n0 + lr) * 512 + kg;

  f32x4 acc[4][4];
  #pragma unroll
  for (int mi = 0; mi < 4; mi++)
    #pragma unroll
    for (int ni = 0; ni < 4; ni++) acc[mi][ni] = (f32x4){0.f, 0.f, 0.f, 0.f};

  #pragma unroll
  for (int ks = 0; ks < 16; ks++) {
    const _Float16* abase = (ks < 8) ? smem : (smem + 64 * APAD);
    const int acol = kg + (ks & 7) * 32;
    half8 a[4], bbv[4];
    #pragma unroll
    for (int mi = 0; mi < 4; mi++)
      a[mi] = *(const half8*)(abase + (mi * 16 + lr) * APAD + acol);
    #pragma unroll
    for (int ni = 0; ni < 4; ni++)
      bbv[ni] = *(const half8*)(bp + (size_t)ni * 16 * 512 + ks * 32);
    #pragma unroll
    for (int mi = 0; mi < 4; mi++)
      #pragma unroll
      for (int ni = 0; ni < 4; ni++)
        acc[mi][ni] = __builtin_amdgcn_mfma_f32_16x16x32_f16(a[mi], bbv[ni], acc[mi][ni], 0, 0, 0);
  }

  __syncthreads();   // all waves done reading A tiles before comb overwrites

  // epilogue 1: + bcomb + a2*cv, store comb tile to LDS (aliases A0 region)
  _Float16* comb = smem;
  #pragma unroll
  for (int ni = 0; ni < 4; ni++) {
    int col = n0 + ni * 16 + lr;
    float bc = bcomb[b * CC + col];
    float a2 = a2g[b * CC + col];
    #pragma unroll
    for (int mi = 0; mi < 4; mi++) {
      #pragma unroll
      for (int j = 0; j < 4; j++) {
        int r = mi * 16 + jr + j;
        size_t idx = (size_t)(r0 + r) * CC + col;
        float v = acc[mi][ni][j] + bc + a2 * (float)cvb[idx];
        comb[r * CPAD + col] = (_Float16)v;
      }
    }
  }
  __syncthreads();

  // ---- phase 2: K=256 GEMM, A from LDS comb, B = proj f16 (L2) ----
  const _Float16* bp2 = pf + (size_t)(n0 + lr) * CC + kg;

  f32x4 acc2[4][4];
  #pragma unroll
  for (int mi = 0; mi < 4; mi++)
    #pragma unroll
    for (int ni = 0; ni < 4; ni++) acc2[mi][ni] = (f32x4){0.f, 0.f, 0.f, 0.f};

  #pragma unroll
  for (int ks = 0; ks < 8; ks++) {
    half8 a[4], bbv[4];
    #pragma unroll
    for (int mi = 0; mi < 4; mi++) {
      const _Float16* s = comb + (mi * 16 + lr) * CPAD + kg + ks * 32;
      half4_t lo = *(const half4_t*)(s);
      half4_t hi = *(const half4_t*)(s + 4);
      a[mi][0] = lo[0]; a[mi][1] = lo[1]; a[mi][2] = lo[2]; a[mi][3] = lo[3];
      a[mi][4] = hi[0]; a[mi][5] = hi[1]; a[mi][6] = hi[2]; a[mi][7] = hi[3];
    }
    #pragma unroll
    for (int ni = 0; ni < 4; ni++)
      bbv[ni] = *(const half8*)(bp2 + (size_t)ni * 16 * CC + ks * 32);
    #pragma unroll
    for (int mi = 0; mi < 4; mi++)
      #pragma unroll
      for (int ni = 0; ni < 4; ni++)
        acc2[mi][ni] = __builtin_amdgcn_mfma_f32_16x16x32_f16(a[mi], bbv[ni], acc2[mi][ni], 0, 0, 0);
  }

  #pragma unroll
  for (int ni = 0; ni < 4; ni++) {
    int col = n0 + ni * 16 + lr;
    float bias = pb[col];
    #pragma unroll
    for (int mi = 0; mi < 4; mi++) {
      #pragma unroll
      for (int j = 0; j < 4; j++) {
        size_t idx = (size_t)(r0 + mi * 16 + jr + j) * CC + col;
        out[idx] = acc2[mi][ni][j] + bias;
      }
    }
  }
}

// ---------------------------------------------------------------------------
extern "C" void kernel_launch(void* const* d_in, const int* in_sizes, int n_in,
                              void* d_out, int out_size, void* d_ws, size_t ws_size,
                              hipStream_t stream)
{
  const float* x    = (const float*)d_in[0];
  const float* off  = (const float*)d_in[1];
  const float* Ww   = (const float*)d_in[2];
  const float* bw   = (const float*)d_in[3];
  const float* Wh   = (const float*)d_in[4];
  const float* bh   = (const float*)d_in[5];
  const float* lw   = (const float*)d_in[6];
  const float* blc  = (const float*)d_in[7];
  const float* fc1w = (const float*)d_in[8];
  const float* fc1b = (const float*)d_in[9];
  const float* fc2w = (const float*)d_in[10];
  const float* fc2b = (const float*)d_in[11];
  const float* pw   = (const float*)d_in[12];
  const float* pb   = (const float*)d_in[13];
  float* out = (float*)d_out;

  char* ws = (char*)d_ws;
  // workspace (peak ~100.3 MB), NO concurrent aliasing (buffer-role rotation):
  //   R0 @ 0    : shb   (k_col writes)
  //   R1 @ 32MB : offAT (k_trans->k_rows reads), THEN cvb (k_conv writes after)
  //   R2 @ 64MB : offBT (k_trans->k_col reads), THEN swb (k_rows writes after)
  //   Bp @ 96MB (4MB); pf/sums/gate/bcomb after
  _Float16* shb   = (_Float16*)(ws + 0);
  _Float16* offAT = (_Float16*)(ws + 33554432);
  _Float16* cvb   = (_Float16*)(ws + 33554432);   // reuses R1 after k_rows
  _Float16* offBT = (_Float16*)(ws + 67108864);
  _Float16* swb   = (_Float16*)(ws + 67108864);   // reuses R2 after k_col
  _Float16* Bp    = (_Float16*)(ws + 100663296);
  _Float16* pf    = (_Float16*)(ws + 104857600);
  float* sums     = (float*)(ws + 104988672);
  float* gate     = (float*)(ws + 105037824);
  float* bcomb    = (float*)(ws + 105086976);
  float* ssw = sums, *ssh = sums + 4096, *scv = sums + 8192;

  hipMemsetAsync(sums, 0, 3 * 4096 * sizeof(float), stream);
  k_trans<<<8192, 256, 0, stream>>>(off, offAT, offBT);
  k_col<<<BB * WW2, 256, 0, stream>>>(x, offBT, shb, ssh);     // consumes offBT
  k_rows<<<BB * HH, 256, 0, stream>>>(x, offAT, swb, ssw);     // consumes offAT, writes R2
  k_conv<<<BB * HH, 256, 0, stream>>>(x, lw, cvb, scv);        // writes R1
  k_gate<<<BB, 256, 0, stream>>>(ssw, ssh, scv, Ww, bw, Wh, bh, blc,
                                 fc1w, fc1b, fc2w, fc2b, gate);
  k_prep<<<BB * CC, 256, 0, stream>>>(gate, Ww, Wh, bw, bh, blc, Bp, bcomb);
  k_cvt<<<CC, 256, 0, stream>>>(pw, pf);
  k_fused<<<1024, 256, 0, stream>>>(swb, shb, Bp, bcomb, gate + 2 * BB * CC,
                                    cvb, pf, pb, out);
}

// Round 8
// 285.176 us; speedup vs baseline: 1.2205x; 1.0302x over previous
//
#include <hip/hip_runtime.h>
#include <hip/hip_bf16.h>

typedef _Float16 half4_t __attribute__((ext_vector_type(4)));
typedef _Float16 half8 __attribute__((ext_vector_type(8)));
typedef float f32x4 __attribute__((ext_vector_type(4)));

#define BB 16
#define HH 64
#define WW2 64
#define CC 256

// ---------------------------------------------------------------------------
// Kernel T: LDS tile transpose of BOTH offset halves to pixel-major f16.
// (validated round 3.)
// ---------------------------------------------------------------------------
__global__ __launch_bounds__(256) void k_trans(const float* __restrict__ off,
                                               _Float16* __restrict__ offAT,
                                               _Float16* __restrict__ offBT)
{
  __shared__ _Float16 tile[64][65];
  const int blk = blockIdx.x;          // b(16) * half(2) * cht(4) * st(64)
  const int st   = blk & 63;
  const int cht  = (blk >> 6) & 3;
  const int half = (blk >> 8) & 1;
  const int b    = blk >> 9;
  const int t = threadIdx.x;

  const int s0 = st * 64;
  const int ch0 = half * 256 + cht * 64;
  const float* src = off + ((size_t)b * 512 + ch0) * 4096 + s0;
  const int sl = t & 63;
  #pragma unroll
  for (int p = 0; p < 16; p++) {
    int chl = (t >> 6) + p * 4;
    tile[chl][sl] = (_Float16)src[(size_t)chl * 4096 + sl];
  }
  __syncthreads();

  _Float16* dst = (half == 0) ? offAT : offBT;
  #pragma unroll
  for (int p = 0; p < 2; p++) {
    int pl = (t >> 3) + p * 32;         // pixel within tile
    int c8 = (t & 7) * 8;
    half8 hv;
    #pragma unroll
    for (int r = 0; r < 8; r++) hv[r] = tile[c8 + r][pl];
    int s = s0 + pl;
    size_t pix = (half == 0) ? ((size_t)b * 4096 + s)
                             : ((size_t)b * 4096 + (s & 63) * 64 + (s >> 6));
    *(half8*)(dst + pix * 256 + cht * 64 + c8) = hv;
  }
}

// ---------------------------------------------------------------------------
// Kernel MT: transpose Ww, Wh (f32 [n][k]) -> WwT, WhT (f16 [k][n]).
// Same LDS-tile pattern as k_trans. 32 tiny blocks; outputs live in d_out
// scratch (consumed by k_mats before k_gemm overwrites d_out).
// ---------------------------------------------------------------------------
__global__ __launch_bounds__(256) void k_matsT(
    const float* __restrict__ Ww, const float* __restrict__ Wh,
    _Float16* __restrict__ WwT, _Float16* __restrict__ WhT)
{
  __shared__ _Float16 tile[64][65];
  const int blk = blockIdx.x;          // mat(2) x kt(4) x nt(4)
  const int nt = blk & 3, kt = (blk >> 2) & 3, mat = blk >> 4;
  const float* src = mat ? Wh : Ww;
  _Float16* dst = mat ? WhT : WwT;
  const int n0 = nt * 64, k0 = kt * 64;
  const int t = threadIdx.x, sl = t & 63;
  #pragma unroll
  for (int p = 0; p < 16; p++) {
    int chl = (t >> 6) + p * 4;        // n-local
    tile[chl][sl] = (_Float16)src[(size_t)(n0 + chl) * 256 + k0 + sl];
  }
  __syncthreads();
  #pragma unroll
  for (int p = 0; p < 2; p++) {
    int pl = (t >> 3) + p * 32;        // k-local
    int c8 = (t & 7) * 8;              // n-local
    half8 hv;
    #pragma unroll
    for (int r = 0; r < 8; r++) hv[r] = tile[c8 + r][pl];
    *(half8*)(dst + (size_t)(k0 + pl) * 256 + n0 + c8) = hv;
  }
}

// ---------------------------------------------------------------------------
// Kernel RS: sw sampling ONLY (validated round 5).
// ---------------------------------------------------------------------------
__global__ __launch_bounds__(256) void k_rows(
    const float* __restrict__ x, const _Float16* __restrict__ offA,
    _Float16* __restrict__ swb, float* __restrict__ ssw)
{
  __shared__ _Float16 xr[WW2 * CC];     // [xi][c], 32 KB

  const int work = (blockIdx.x & 7) * 128 + (blockIdx.x >> 3);  // 1024 blocks
  const int b = work >> 6, y = work & 63;
  const int t = threadIdx.x;
  const int c = t;

  const float* xrow_src = x + (size_t)(b * HH + y) * WW2 * CC;
  #pragma unroll
  for (int p = 0; p < 16; p++) {
    int i = p * 1024 + t * 4;
    float4 v = *(const float4*)(xrow_src + i);
    half4_t h = {(_Float16)v.x, (_Float16)v.y, (_Float16)v.z, (_Float16)v.w};
    *(half4_t*)(xr + i) = h;
  }
  __syncthreads();

  const _Float16* op = offA + ((size_t)b * 4096 + y * 64) * CC + c;
  _Float16* sp = swb + ((size_t)b * 4096 + y * 64) * CC + c;
  float asw = 0.f;

  #pragma unroll 8
  for (int xi = 0; xi < 64; xi++) {
    float dx = (float)op[(size_t)xi * CC];
    float xs = (float)xi + dx;
    float xf = floorf(xs);
    float wx = xs - xf;
    int xq = (int)xf;
    float v0 = (xq >= 0 && xq < WW2) ? (float)xr[xq * CC + c] : 0.f;
    float v1 = (xq + 1 >= 0 && xq + 1 < WW2) ? (float)xr[(xq + 1) * CC + c] : 0.f;
    float swv = (1.f - wx) * v0 + wx * v1;
    sp[(size_t)xi * CC] = (_Float16)swv;
    asw += swv;
  }
  atomicAdd(&ssw[b * CC + c], asw);
}

// ---------------------------------------------------------------------------
// Kernel V: depthwise 5x5 conv ONLY (validated round 5).
// ---------------------------------------------------------------------------
__global__ __launch_bounds__(256) void k_conv(
    const float* __restrict__ x, const float* __restrict__ lw,
    _Float16* __restrict__ cvb, float* __restrict__ scv)
{
  const int work = (blockIdx.x & 7) * 128 + (blockIdx.x >> 3);  // 1024 blocks
  const int b = work >> 6, y = work & 63;
  const int c = threadIdx.x;

  float wgt[25];
  #pragma unroll
  for (int q = 0; q < 25; q++) wgt[q] = lw[c * 25 + q];

  const float* xb = x + (size_t)b * HH * WW2 * CC + c;
  const float* rp[5];
  bool yv[5];
  #pragma unroll
  for (int ky = 0; ky < 5; ky++) {
    int yy = y + ky - 2;
    yv[ky] = (yy >= 0 && yy < HH);
    rp[ky] = xb + (size_t)(yv[ky] ? yy : 0) * WW2 * CC;
  }

  _Float16* cp = cvb + ((size_t)b * 4096 + y * 64) * CC + c;
  float acc5[5] = {0.f, 0.f, 0.f, 0.f, 0.f};
  float acv = 0.f;

  #pragma unroll 5
  for (int u = 0; u < 70; ++u) {
    acc5[(u + 2) % 5] = 0.f;                 // slot for new output v=u+2
    if (u < 64) {
      float c0 = yv[0] ? rp[0][u * CC] : 0.f;
      float c1 = yv[1] ? rp[1][u * CC] : 0.f;
      float c2 = yv[2] ? rp[2][u * CC] : 0.f;
      float c3 = yv[3] ? rp[3][u * CC] : 0.f;
      float c4 = yv[4] ? rp[4][u * CC] : 0.f;
      #pragma unroll
      for (int kx = 0; kx < 5; kx++) {
        acc5[(u + 7 - kx) % 5] += wgt[0 + kx] * c0 + wgt[5 + kx] * c1 +
                                  wgt[10 + kx] * c2 + wgt[15 + kx] * c3 +
                                  wgt[20 + kx] * c4;
      }
    }
    int xi = u - 2;
    if (xi >= 0 && xi < 64) {
      float cv = acc5[(u + 3) % 5];
      cp[(size_t)xi * CC] = (_Float16)cv;
      acv += cv;
    }
  }
  atomicAdd(&scv[b * CC + c], acv);
}

// ---------------------------------------------------------------------------
// Kernel C: sh sampling (validated round 5).
// ---------------------------------------------------------------------------
__global__ __launch_bounds__(256) void k_col(
    const float* __restrict__ x, const _Float16* __restrict__ offBT,
    _Float16* __restrict__ shb, float* __restrict__ ssh)
{
  __shared__ _Float16 xc[HH * CC];      // [y][c]
  const int work = (blockIdx.x & 7) * 128 + (blockIdx.x >> 3);  // 1024 blocks
  const int b = work >> 6, xi = work & 63;
  const int t = threadIdx.x;
  const int c = t;

  #pragma unroll
  for (int p = 0; p < 16; p++) {
    int yy = p * 4 + (t >> 6);
    int c4 = (t & 63) * 4;
    float4 v = *(const float4*)(x + ((size_t)(b * HH + yy) * WW2 + xi) * CC + c4);
    half4_t h = {(_Float16)v.x, (_Float16)v.y, (_Float16)v.z, (_Float16)v.w};
    *(half4_t*)(xc + yy * CC + c4) = h;
  }
  __syncthreads();

  const _Float16* obt = offBT + ((size_t)(b * WW2 + xi) * HH) * CC + c;
  _Float16* hp = shb + ((size_t)(b * HH) * WW2 + xi) * CC + c;
  float ash = 0.f;
  #pragma unroll 8
  for (int yy = 0; yy < 64; yy++) {
    float dy = (float)obt[(size_t)yy * CC];
    float ys = (float)yy + dy;
    float yf = floorf(ys);
    float wy = ys - yf;
    int yq = (int)yf;
    float u0 = (yq >= 0 && yq < HH) ? (float)xc[yq * CC + c] : 0.f;
    float u1 = (yq + 1 >= 0 && yq + 1 < HH) ? (float)xc[(yq + 1) * CC + c] : 0.f;
    float shv = (1.f - wy) * u0 + wy * u1;
    hp[(size_t)yy * WW2 * CC] = (_Float16)shv;
    ash += shv;
  }
  atomicAdd(&ssh[b * CC + c], ash);
}

// ---------------------------------------------------------------------------
// Kernel B: gating MLP. Outputs f16 gate table gh[3][16][256] + combined
// bias bcomb[b][n] = a0*bw + a1*bh + a2*blc (f32).
// ---------------------------------------------------------------------------
__global__ __launch_bounds__(256) void k_gate(
    const float* __restrict__ ssw, const float* __restrict__ ssh, const float* __restrict__ scv,
    const float* __restrict__ Ww, const float* __restrict__ bw,
    const float* __restrict__ Wh, const float* __restrict__ bh,
    const float* __restrict__ blc,
    const float* __restrict__ fc1w, const float* __restrict__ fc1b,
    const float* __restrict__ fc2w, const float* __restrict__ fc2b,
    _Float16* __restrict__ gh, float* __restrict__ bcomb)
{
  __shared__ float sswl[CC], sshl[CC], avgl[CC], tl[64];
  const int b = blockIdx.x, tid = threadIdx.x;
  sswl[tid] = ssw[b * CC + tid];
  sshl[tid] = ssh[b * CC + tid];
  __syncthreads();

  float acc = scv[b * CC + tid];
  for (int c = 0; c < CC; c++)
    acc += sswl[c] * Ww[tid * CC + c] + sshl[c] * Wh[tid * CC + c];
  avgl[tid] = acc * (1.f / (HH * WW2)) + bw[tid] + bh[tid] + blc[tid];
  __syncthreads();

  if (tid < 64) {
    float a = fc1b[tid];
    for (int o = 0; o < CC; o++) a += avgl[o] * fc1w[tid * CC + o];
    tl[tid] = 0.5f * a * (1.f + erff(a * 0.70710678118654752f));
  }
  __syncthreads();

  float g[3];
  #pragma unroll
  for (int j = 0; j < 3; j++) {
    float a = fc2b[tid * 3 + j];
    for (int k = 0; k < 64; k++) a += tl[k] * fc2w[(tid * 3 + j) * 64 + k];
    g[j] = a;
  }
  float m = fmaxf(g[0], fmaxf(g[1], g[2]));
  float e0 = expf(g[0] - m), e1 = expf(g[1] - m), e2 = expf(g[2] - m);
  float inv = 1.f / (e0 + e1 + e2);
  float a0 = e0 * inv, a1 = e1 * inv, a2 = e2 * inv;
  gh[(0 * BB + b) * CC + tid] = (_Float16)a0;
  gh[(1 * BB + b) * CC + tid] = (_Float16)a1;
  gh[(2 * BB + b) * CC + tid] = (_Float16)a2;
  bcomb[b * CC + tid] = a0 * bw[tid] + a1 * bh[tid] + a2 * blc[tid];
}

__global__ __launch_bounds__(256) void k_cvt(const float* __restrict__ pw,
                                             _Float16* __restrict__ pf)
{
  int i = blockIdx.x * 256 + threadIdx.x;
  pf[i] = (_Float16)pw[i];
}

// ---------------------------------------------------------------------------
// Kernel M: build per-batch collapsed weights
//   Bcat[b][o][k]      = sum_n a0[b,n]*Ww[n,k]*pw[o,n]   (k <  256, br=0)
//   Bcat[b][o][256+k]  = sum_n a1[b,n]*Wh[n,k]*pw[o,n]   (br=1)
// via MFMA: A[o,n] = pf[o,n]*a_br[n], B[k,n] = W_brT[k,n]. Also (br==0)
// bias_out[b][o] = sum_n bcomb[b,n]*pw[o,n] + pb[o].
// grid 128 blocks = b(16) x br(2) x oblk(4).
// ---------------------------------------------------------------------------
__global__ __launch_bounds__(256) void k_mats(
    const _Float16* __restrict__ pf, const _Float16* __restrict__ gh,
    const _Float16* __restrict__ WwT, const _Float16* __restrict__ WhT,
    const float* __restrict__ bcomb, const float* __restrict__ pb,
    _Float16* __restrict__ Bcat, float* __restrict__ bias_out)
{
  const int blk = (blockIdx.x & 7) * 16 + (blockIdx.x >> 3);  // 128 blocks
  const int ob = blk & 3;
  const int br = (blk >> 2) & 1;
  const int b  = blk >> 3;
  const int o0 = ob * 64;
  const int tid = threadIdx.x;
  const int wid = tid >> 6, l = tid & 63;
  const int n0 = wid * 64;             // k-column block
  const int lr = l & 15;
  const int kg = (l >> 4) * 8;
  const int jr = (l >> 4) * 4;

  const _Float16* WT  = br ? WhT : WwT;
  const _Float16* ghb = gh + (size_t)(br * BB + b) * CC;

  f32x4 acc[4][4];
  #pragma unroll
  for (int mi = 0; mi < 4; mi++)
    #pragma unroll
    for (int ni = 0; ni < 4; ni++) acc[mi][ni] = (f32x4){0.f, 0.f, 0.f, 0.f};

  #pragma unroll
  for (int ks = 0; ks < 8; ks++) {
    half8 gv = *(const half8*)(ghb + kg + ks * 32);
    half8 a[4], bbv[4];
    #pragma unroll
    for (int mi = 0; mi < 4; mi++)
      a[mi] = *(const half8*)(pf + (size_t)(o0 + mi * 16 + lr) * CC + kg + ks * 32) * gv;
    #pragma unroll
    for (int ni = 0; ni < 4; ni++)
      bbv[ni] = *(const half8*)(WT + (size_t)(n0 + ni * 16 + lr) * CC + kg + ks * 32);
    #pragma unroll
    for (int mi = 0; mi < 4; mi++)
      #pragma unroll
      for (int ni = 0; ni < 4; ni++)
        acc[mi][ni] = __builtin_amdgcn_mfma_f32_16x16x32_f16(a[mi], bbv[ni], acc[mi][ni], 0, 0, 0);
  }

  #pragma unroll
  for (int ni = 0; ni < 4; ni++) {
    int kcol = n0 + ni * 16 + lr;
    #pragma unroll
    for (int mi = 0; mi < 4; mi++) {
      #pragma unroll
      for (int j = 0; j < 4; j++) {
        int o = o0 + mi * 16 + jr + j;
        Bcat[((size_t)b * CC + o) * 512 + br * 256 + kcol] = (_Float16)acc[mi][ni][j];
      }
    }
  }

  if (br == 0) {
    int o_l = tid >> 2, part = tid & 3;
    const _Float16* pr = pf + (size_t)(o0 + o_l) * CC + part * 64;
    const float* bc = bcomb + b * CC + part * 64;
    float s = 0.f;
    #pragma unroll
    for (int i = 0; i < 8; i++) {
      half8 h = *(const half8*)(pr + i * 8);
      #pragma unroll
      for (int r = 0; r < 8; r++) s += (float)h[r] * bc[i * 8 + r];
    }
    s += __shfl_xor(s, 1);
    s += __shfl_xor(s, 2);
    if (part == 0) bias_out[b * CC + o0 + o_l] = s + pb[o0 + o_l];
  }
}

// ---------------------------------------------------------------------------
// Kernel G: single K=768 GEMM.  out = [sw|sh|cv] @ Bcat' + bias_out.
// One 33KB LDS A-buffer rotated sw->sh->cv, register prefetch of the next
// tile issued before the current compute phase. cv phase's B-fragment is
// pf*a2 computed on the fly (M2 = diag(a2)P^T never materialized).
// ---------------------------------------------------------------------------
#define APAD 264
__global__ __launch_bounds__(256) void k_gemm(
    const _Float16* __restrict__ swb, const _Float16* __restrict__ shb,
    const _Float16* __restrict__ cvb, const _Float16* __restrict__ Bcat,
    const _Float16* __restrict__ pf, const _Float16* __restrict__ a2h,
    const float* __restrict__ bias_out, float* __restrict__ out)
{
  __shared__ _Float16 smem[64 * APAD];  // 33,792 B -> 4 blocks/CU (LDS)

  const int work = (blockIdx.x & 7) * 128 + (blockIdx.x >> 3);  // 1024 blocks
  const int r0 = work * 64;
  const int b = work >> 6;
  const int tid = threadIdx.x;
  const int wid = tid >> 6, l = tid & 63;
  const int n0 = wid * 64;
  const int lr = l & 15;
  const int kg = (l >> 4) * 8;
  const int jr = (l >> 4) * 4;

  const _Float16* bq = Bcat + ((size_t)b * CC + n0 + lr) * 512 + kg;

  f32x4 acc[4][4];
  #pragma unroll
  for (int mi = 0; mi < 4; mi++)
    #pragma unroll
    for (int ni = 0; ni < 4; ni++) acc[mi][ni] = (f32x4){0.f, 0.f, 0.f, 0.f};

  half8 st[8];
  // stage sw
  {
    const _Float16* g = swb + (size_t)r0 * CC;
    #pragma unroll
    for (int p = 0; p < 8; p++) st[p] = *(const half8*)(g + p * 2048 + tid * 8);
    #pragma unroll
    for (int p = 0; p < 8; p++) {
      int i = p * 2048 + tid * 8;
      *(half8*)(smem + (i >> 8) * APAD + (i & 255)) = st[p];
    }
  }
  __syncthreads();
  // prefetch sh (completes during sw phase)
  {
    const _Float16* g = shb + (size_t)r0 * CC;
    #pragma unroll
    for (int p = 0; p < 8; p++) st[p] = *(const half8*)(g + p * 2048 + tid * 8);
  }
  // ---- phase A: sw, ks 0..7 ----
  #pragma unroll
  for (int ks = 0; ks < 8; ks++) {
    half8 a[4], bbv[4];
    #pragma unroll
    for (int mi = 0; mi < 4; mi++)
      a[mi] = *(const half8*)(smem + (mi * 16 + lr) * APAD + kg + ks * 32);
    #pragma unroll
    for (int ni = 0; ni < 4; ni++)
      bbv[ni] = *(const half8*)(bq + (size_t)ni * 16 * 512 + ks * 32);
    #pragma unroll
    for (int mi = 0; mi < 4; mi++)
      #pragma unroll
      for (int ni = 0; ni < 4; ni++)
        acc[mi][ni] = __builtin_amdgcn_mfma_f32_16x16x32_f16(a[mi], bbv[ni], acc[mi][ni], 0, 0, 0);
  }
  __syncthreads();
  #pragma unroll
  for (int p = 0; p < 8; p++) {
    int i = p * 2048 + tid * 8;
    *(half8*)(smem + (i >> 8) * APAD + (i & 255)) = st[p];
  }
  __syncthreads();
  // prefetch cv (completes during sh phase)
  {
    const _Float16* g = cvb + (size_t)r0 * CC;
    #pragma unroll
    for (int p = 0; p < 8; p++) st[p] = *(const half8*)(g + p * 2048 + tid * 8);
  }
  // ---- phase B: sh, ks 0..7 (Bcat cols 256..511) ----
  #pragma unroll
  for (int ks = 0; ks < 8; ks++) {
    half8 a[4], bbv[4];
    #pragma unroll
    for (int mi = 0; mi < 4; mi++)
      a[mi] = *(const half8*)(smem + (mi * 16 + lr) * APAD + kg + ks * 32);
    #pragma unroll
    for (int ni = 0; ni < 4; ni++)
      bbv[ni] = *(const half8*)(bq + (size_t)ni * 16 * 512 + 256 + ks * 32);
    #pragma unroll
    for (int mi = 0; mi < 4; mi++)
      #pragma unroll
      for (int ni = 0; ni < 4; ni++)
        acc[mi][ni] = __builtin_amdgcn_mfma_f32_16x16x32_f16(a[mi], bbv[ni], acc[mi][ni], 0, 0, 0);
  }
  __syncthreads();
  #pragma unroll
  for (int p = 0; p < 8; p++) {
    int i = p * 2048 + tid * 8;
    *(half8*)(smem + (i >> 8) * APAD + (i & 255)) = st[p];
  }
  __syncthreads();
  // ---- phase C: cv, ks 0..7, B-frag = pf * a2 on the fly ----
  const _Float16* a2b = a2h + (size_t)b * CC;
  #pragma unroll
  for (int ks = 0; ks < 8; ks++) {
    half8 a2v = *(const half8*)(a2b + kg + ks * 32);
    half8 a[4], bbv[4];
    #pragma unroll
    for (int mi = 0; mi < 4; mi++)
      a[mi] = *(const half8*)(smem + (mi * 16 + lr) * APAD + kg + ks * 32);
    #pragma unroll
    for (int ni = 0; ni < 4; ni++)
      bbv[ni] = *(const half8*)(pf + (size_t)(n0 + ni * 16 + lr) * CC + kg + ks * 32) * a2v;
    #pragma unroll
    for (int mi = 0; mi < 4; mi++)
      #pragma unroll
      for (int ni = 0; ni < 4; ni++)
        acc[mi][ni] = __builtin_amdgcn_mfma_f32_16x16x32_f16(a[mi], bbv[ni], acc[mi][ni], 0, 0, 0);
  }

  // epilogue
  #pragma unroll
  for (int ni = 0; ni < 4; ni++) {
    int col = n0 + ni * 16 + lr;
    float bo = bias_out[b * CC + col];
    #pragma unroll
    for (int mi = 0; mi < 4; mi++) {
      #pragma unroll
      for (int j = 0; j < 4; j++) {
        size_t idx = (size_t)(r0 + mi * 16 + jr + j) * CC + col;
        out[idx] = acc[mi][ni][j] + bo;
      }
    }
  }
}

// ---------------------------------------------------------------------------
extern "C" void kernel_launch(void* const* d_in, const int* in_sizes, int n_in,
                              void* d_out, int out_size, void* d_ws, size_t ws_size,
                              hipStream_t stream)
{
  const float* x    = (const float*)d_in[0];
  const float* off  = (const float*)d_in[1];
  const float* Ww   = (const float*)d_in[2];
  const float* bw   = (const float*)d_in[3];
  const float* Wh   = (const float*)d_in[4];
  const float* bh   = (const float*)d_in[5];
  const float* lw   = (const float*)d_in[6];
  const float* blc  = (const float*)d_in[7];
  const float* fc1w = (const float*)d_in[8];
  const float* fc1b = (const float*)d_in[9];
  const float* fc2w = (const float*)d_in[10];
  const float* fc2b = (const float*)d_in[11];
  const float* pw   = (const float*)d_in[12];
  const float* pb   = (const float*)d_in[13];
  float* out = (float*)d_out;

  char* ws = (char*)d_ws;
  // ws regions (validated rotation, peak ~100.2 MiB):
  //   R0 @ 0    : shb
  //   R1 @ 32MB : offAT -> cvb
  //   R2 @ 64MB : offBT -> swb
  //   tail @ 96MiB: Bcat 4MiB | pf 128K | gh 24K | bcomb 16K | bias_out 16K
  _Float16* shb   = (_Float16*)(ws + 0);
  _Float16* offAT = (_Float16*)(ws + 33554432);
  _Float16* cvb   = (_Float16*)(ws + 33554432);   // reuses R1 after k_rows
  _Float16* offBT = (_Float16*)(ws + 67108864);
  _Float16* swb   = (_Float16*)(ws + 67108864);   // reuses R2 after k_col
  _Float16* Bcat  = (_Float16*)(ws + 100663296);  // 4,194,304 B
  _Float16* pf    = (_Float16*)(ws + 104857600);  //   131,072 B
  _Float16* gh    = (_Float16*)(ws + 104988672);  //    24,576 B  [3][16][256]
  float* bcomb    = (float*)(ws + 105013248);     //    16,384 B
  float* bias_out = (float*)(ws + 105029632);     //    16,384 B
  // d_out scratch (all consumed before k_gemm writes out):
  _Float16* WwT = (_Float16*)((char*)d_out + 0);        // 131,072 B
  _Float16* WhT = (_Float16*)((char*)d_out + 131072);   // 131,072 B
  float* sums   = (float*)((char*)d_out + 262144);      //  49,152 B
  float* ssw = sums, *ssh = sums + 4096, *scv = sums + 8192;

  hipMemsetAsync(sums, 0, 3 * 4096 * sizeof(float), stream);
  k_matsT<<<32, 256, 0, stream>>>(Ww, Wh, WwT, WhT);
  k_trans<<<8192, 256, 0, stream>>>(off, offAT, offBT);
  k_col<<<BB * WW2, 256, 0, stream>>>(x, offBT, shb, ssh);     // consumes offBT
  k_rows<<<BB * HH, 256, 0, stream>>>(x, offAT, swb, ssw);     // consumes offAT
  k_conv<<<BB * HH, 256, 0, stream>>>(x, lw, cvb, scv);
  k_gate<<<BB, 256, 0, stream>>>(ssw, ssh, scv, Ww, bw, Wh, bh, blc,
                                 fc1w, fc1b, fc2w, fc2b, gh, bcomb);
  k_cvt<<<CC, 256, 0, stream>>>(pw, pf);
  k_mats<<<128, 256, 0, stream>>>(pf, gh, WwT, WhT, bcomb, pb, Bcat, bias_out);
  k_gemm<<<1024, 256, 0, stream>>>(swb, shb, cvb, Bcat, pf, gh + 2 * BB * CC,
                                   bias_out, out);
}